// Round 1
// baseline (2074.399 us; speedup 1.0000x reference)
//
#include <hip/hip_runtime.h>
#include <math.h>

// MHA forward: B=2, S=2048, D=1024, H=16, DH=64
// Outputs: out [2,2048,1024] then weights [2,16,2048,2048], both fp32.

#define TILE_M 64
#define TILE_N 64
#define TILE_K 16

// C[M,N] = alpha * A[M,K] @ B(K,N) (+ bias), batched over gridDim.z with
// z -> (bb = z/hdiv, hh = z%hdiv) and per-operand (bb,hh) strides.
// TRANS_B: logical B[k][n] = Bmat[n*ldb + k]   (for Q @ K^T)
template <bool TRANS_B>
__global__ __launch_bounds__(256) void gemm_kernel(
    const float* __restrict__ A, const float* __restrict__ B,
    const float* __restrict__ bias, float* __restrict__ C, int M, int N, int K,
    int lda, int ldb, int ldc, size_t sAb, size_t sAh, size_t sBb, size_t sBh,
    size_t sCb, size_t sCh, int hdiv, float alpha) {
  __shared__ float As[TILE_K][TILE_M + 1];
  __shared__ float Bs[TILE_K][TILE_N + 1];

  const int z = blockIdx.z;
  const int bb = z / hdiv, hh = z % hdiv;
  const float* Ab = A + (size_t)bb * sAb + (size_t)hh * sAh;
  const float* Bb = B + (size_t)bb * sBb + (size_t)hh * sBh;
  float* Cb = C + (size_t)bb * sCb + (size_t)hh * sCh;

  const int row0 = blockIdx.y * TILE_M;
  const int col0 = blockIdx.x * TILE_N;
  const int tid = threadIdx.x;
  const int tx = tid % 16, ty = tid / 16;

  float acc[4][4] = {};

  const int am = tid / 4;        // 0..63
  const int ak = (tid % 4) * 4;  // 0,4,8,12

  for (int k0 = 0; k0 < K; k0 += TILE_K) {
    // A tile: 64 rows x 16 k, one float4 per thread, stored transposed
    {
      const float* src = Ab + (size_t)(row0 + am) * lda + (k0 + ak);
      const float4 va = *(const float4*)src;
      As[ak + 0][am] = va.x;
      As[ak + 1][am] = va.y;
      As[ak + 2][am] = va.z;
      As[ak + 3][am] = va.w;
    }
    if (TRANS_B) {
      // Bs[kk][n] = Bmat[(col0+n)*ldb + k0+kk]
      const float* src = Bb + (size_t)(col0 + am) * ldb + (k0 + ak);
      const float4 vb = *(const float4*)src;
      Bs[ak + 0][am] = vb.x;
      Bs[ak + 1][am] = vb.y;
      Bs[ak + 2][am] = vb.z;
      Bs[ak + 3][am] = vb.w;
    } else {
      const int bk = tid / 64;  // 0..3
      const int bn = tid % 64;
#pragma unroll
      for (int i = 0; i < 4; i++) {
        Bs[bk + i * 4][bn] = Bb[(size_t)(k0 + bk + i * 4) * ldb + (col0 + bn)];
      }
    }
    __syncthreads();

#pragma unroll
    for (int kk = 0; kk < TILE_K; kk++) {
      float a[4], b[4];
#pragma unroll
      for (int i = 0; i < 4; i++) a[i] = As[kk][ty * 4 + i];
#pragma unroll
      for (int j = 0; j < 4; j++) b[j] = Bs[kk][tx * 4 + j];
#pragma unroll
      for (int i = 0; i < 4; i++)
#pragma unroll
        for (int j = 0; j < 4; j++) acc[i][j] += a[i] * b[j];
    }
    __syncthreads();
  }

#pragma unroll
  for (int i = 0; i < 4; i++) {
    const int r = row0 + ty * 4 + i;
#pragma unroll
    for (int j = 0; j < 4; j++) {
      const int c = col0 + tx * 4 + j;
      float v = alpha * acc[i][j];
      if (bias) v += bias[c];
      Cb[(size_t)r * ldc + c] = v;
    }
  }
}

// In-place row softmax: one block (256 thr) per row of 2048.
__global__ __launch_bounds__(256) void softmax_kernel(float* __restrict__ w) {
  const size_t row = blockIdx.x;
  float* p = w + row * 2048;
  const int tid = threadIdx.x;
  const int wave = tid >> 6, lane = tid & 63;

  float v[8];
  float m = -1e30f;
#pragma unroll
  for (int i = 0; i < 8; i++) {
    v[i] = p[tid + i * 256];
    m = fmaxf(m, v[i]);
  }
#pragma unroll
  for (int off = 32; off > 0; off >>= 1) m = fmaxf(m, __shfl_xor(m, off, 64));
  __shared__ float redm[4];
  if (lane == 0) redm[wave] = m;
  __syncthreads();
  m = fmaxf(fmaxf(redm[0], redm[1]), fmaxf(redm[2], redm[3]));

  float s = 0.f;
#pragma unroll
  for (int i = 0; i < 8; i++) {
    v[i] = __expf(v[i] - m);
    s += v[i];
  }
#pragma unroll
  for (int off = 32; off > 0; off >>= 1) s += __shfl_xor(s, off, 64);
  __shared__ float reds[4];
  if (lane == 0) reds[wave] = s;
  __syncthreads();
  s = reds[0] + reds[1] + reds[2] + reds[3];

  const float inv = 1.0f / s;
#pragma unroll
  for (int i = 0; i < 8; i++) p[tid + i * 256] = v[i] * inv;
}

extern "C" void kernel_launch(void* const* d_in, const int* in_sizes, int n_in,
                              void* d_out, int out_size, void* d_ws,
                              size_t ws_size, hipStream_t stream) {
  const float* x = (const float*)d_in[0];
  const float* wq = (const float*)d_in[1];
  const float* bq = (const float*)d_in[2];
  const float* wk = (const float*)d_in[3];
  const float* bk = (const float*)d_in[4];
  const float* wv = (const float*)d_in[5];
  const float* bv = (const float*)d_in[6];
  const float* wo = (const float*)d_in[7];
  const float* bo = (const float*)d_in[8];

  const int Bz = 2, S = 2048, D = 1024, H = 16;
  const size_t MS = (size_t)Bz * S;  // 4096 rows

  float* out = (float*)d_out;                  // [2,2048,1024]
  float* wts = out + (size_t)Bz * S * D;       // [2,16,2048,2048]

  float* Q = (float*)d_ws;
  float* Kt = Q + MS * D;
  float* V = Kt + MS * D;
  float* Att = V + MS * D;  // total 64 MB of ws

  dim3 blk(256);

  // ---- Q/K/V projections: [4096,1024] = x @ w + b ----
  dim3 gproj(D / TILE_N, (int)(MS / TILE_M), 1);
  gemm_kernel<false><<<gproj, blk, 0, stream>>>(x, wq, bq, Q, (int)MS, D, D, D,
                                                D, D, 0, 0, 0, 0, 0, 0, 1, 1.f);
  gemm_kernel<false><<<gproj, blk, 0, stream>>>(x, wk, bk, Kt, (int)MS, D, D, D,
                                                D, D, 0, 0, 0, 0, 0, 0, 1, 1.f);
  gemm_kernel<false><<<gproj, blk, 0, stream>>>(x, wv, bv, V, (int)MS, D, D, D,
                                                D, D, 0, 0, 0, 0, 0, 0, 1, 1.f);

  // ---- scores = (Q_h @ K_h^T) * 1/8  ->  weights buffer (raw) ----
  dim3 gsc(S / TILE_N, S / TILE_M, Bz * H);
  gemm_kernel<true><<<gsc, blk, 0, stream>>>(
      Q, Kt, nullptr, wts, S, S, 64, D, D, S, (size_t)S * D, 64, (size_t)S * D,
      64, (size_t)H * S * S, (size_t)S * S, H, 0.125f);

  // ---- softmax rows in-place ----
  softmax_kernel<<<(int)(Bz * H * S), blk, 0, stream>>>(wts);

  // ---- attended_h = weights_h @ V_h ----
  dim3 gav(64 / TILE_N, S / TILE_M, Bz * H);
  gemm_kernel<false><<<gav, blk, 0, stream>>>(
      wts, V, nullptr, Att, S, 64, S, S, D, D, (size_t)H * S * S,
      (size_t)S * S, (size_t)S * D, 64, (size_t)S * D, 64, H, 1.f);

  // ---- out = attended @ wo + bo ----
  gemm_kernel<false><<<gproj, blk, 0, stream>>>(Att, wo, bo, out, (int)MS, D, D,
                                                D, D, D, 0, 0, 0, 0, 0, 0, 1,
                                                1.f);
}